// Round 1
// baseline (121.446 us; speedup 1.0000x reference)
//
#include <hip/hip_runtime.h>

// span(L,i)[b,d] = sum_{k=1..L} tensor[b, i+k, d], written to
// out[b, offL + i, d] where offL = sum_{l<L}(S-l).
// One thread per (b, i, d4): running float4 accumulator over L, 8 loads + 8 stores.
__global__ __launch_bounds__(256) void span_sums_kernel(
    const float4* __restrict__ in,        // [B, S, D/4]
    float4* __restrict__ out,             // [B, Ssum, D/4]
    const int* __restrict__ maxspan_ptr)  // single int (=8)
{
    constexpr int B = 8, S = 512, D4 = 192;  // D = 768 floats = 192 float4
    const int Lmax = *maxspan_ptr;

    const int tid = blockIdx.x * blockDim.x + threadIdx.x;
    const int total = B * (S - 1) * D4;
    if (tid >= total) return;

    const int d4 = tid % D4;
    const int rest = tid / D4;
    const int i = rest % (S - 1);   // span start offset (token index 1+i)
    const int b = rest / (S - 1);

    // total output rows per batch: sum_{L=1..Lmax} (S - L)
    const int Ssum = Lmax * S - (Lmax * (Lmax + 1)) / 2;

    const float4* inb = in + (size_t)b * S * D4;
    const size_t out_base = (size_t)b * Ssum * D4;

    int Lcap = S - 1 - i;
    if (Lcap > Lmax) Lcap = Lmax;

    float4 acc = make_float4(0.f, 0.f, 0.f, 0.f);
    int offL = 0;  // row offset of span-length-L block within a batch (L=1 -> 0)
    for (int L = 1; L <= Lcap; ++L) {
        const float4 v = inb[(size_t)(i + L) * D4 + d4];
        acc.x += v.x; acc.y += v.y; acc.z += v.z; acc.w += v.w;
        out[out_base + (size_t)(offL + i) * D4 + d4] = acc;
        offL += S - L;
    }
}

extern "C" void kernel_launch(void* const* d_in, const int* in_sizes, int n_in,
                              void* d_out, int out_size, void* d_ws, size_t ws_size,
                              hipStream_t stream) {
    const float* tensor = (const float*)d_in[0];
    const int* maxspan = (const int*)d_in[1];
    float* out = (float*)d_out;

    constexpr int B = 8, S = 512, D4 = 192;
    const int total = B * (S - 1) * D4;       // 784,896 threads
    const int block = 256;
    const int grid = (total + block - 1) / block;  // 3066

    span_sums_kernel<<<grid, block, 0, stream>>>(
        (const float4*)tensor, (float4*)out, maxspan);
}

// Round 3
// 121.294 us; speedup vs baseline: 1.0013x; 1.0013x over previous
//
#include <hip/hip_runtime.h>

// span(L,i)[b,d] = sum_{k=1..L} tensor[b, i+k, d] -> out[b, offL(L)+i, d]
// offL(L) = (L-1)*S - (L-1)*L/2.  B=8, S=512, D=768 (192 float4), Lmax=8.
// One thread per (b, i, d4). Fast path (Lmax==8, full span): 8 independent
// loads -> register prefix sum -> 8 stores at compile-time row offsets.
// NOTE: R2 used __builtin_nontemporal_store and core-dumped at first launch;
// plain stores hit full write BW anyway (harness fill = 6.5 TB/s).

__global__ __launch_bounds__(256) void span_sums_kernel(
    const float4* __restrict__ in,        // [B, S, D4]
    float4* __restrict__ out,             // [B, Ssum, D4]
    const int* __restrict__ maxspan_ptr)
{
    constexpr int B = 8, S = 512, D4 = 192;
    const int Lmax = *maxspan_ptr;          // wave-uniform (scalar-loaded)

    const int tid = blockIdx.x * blockDim.x + threadIdx.x;
    const int total = B * (S - 1) * D4;     // 784,896 = 3066 * 256 exactly
    if (tid >= total) return;

    const int d4   = tid % D4;
    const int rest = tid / D4;
    const int i    = rest % (S - 1);        // span start = token 1+i
    const int b    = rest / (S - 1);

    const int Ssum = Lmax * S - (Lmax * (Lmax + 1)) / 2;   // 4060 for Lmax=8

    const float4* ip = in  + ((size_t)b * S    + (size_t)(i + 1)) * D4 + d4;
    float4*       op = out + ((size_t)b * Ssum + (size_t)i)       * D4 + d4;

    if (Lmax == 8 && i <= S - 1 - 8) {
        // 8 independent loads: full MLP, one waitcnt group.
        float4 v0 = ip[0 * D4];
        float4 v1 = ip[1 * D4];
        float4 v2 = ip[2 * D4];
        float4 v3 = ip[3 * D4];
        float4 v4 = ip[4 * D4];
        float4 v5 = ip[5 * D4];
        float4 v6 = ip[6 * D4];
        float4 v7 = ip[7 * D4];
        // register prefix sum
        v1.x += v0.x; v1.y += v0.y; v1.z += v0.z; v1.w += v0.w;
        v2.x += v1.x; v2.y += v1.y; v2.z += v1.z; v2.w += v1.w;
        v3.x += v2.x; v3.y += v2.y; v3.z += v2.z; v3.w += v2.w;
        v4.x += v3.x; v4.y += v3.y; v4.z += v3.z; v4.w += v3.w;
        v5.x += v4.x; v5.y += v4.y; v5.z += v4.z; v5.w += v4.w;
        v6.x += v5.x; v6.y += v5.y; v6.z += v5.z; v6.w += v5.w;
        v7.x += v6.x; v7.y += v6.y; v7.z += v6.z; v7.w += v6.w;
        // compile-time row offsets: offL(L) = {0,511,1021,1530,2038,2545,3051,3556}
        op[0    * D4] = v0;
        op[511  * D4] = v1;
        op[1021 * D4] = v2;
        op[1530 * D4] = v3;
        op[2038 * D4] = v4;
        op[2545 * D4] = v5;
        op[3051 * D4] = v6;
        op[3556 * D4] = v7;
    } else {
        // generic fallback (tail rows i > S-1-Lmax, or Lmax != 8)
        int Lcap = S - 1 - i;
        if (Lcap > Lmax) Lcap = Lmax;
        float4 acc = make_float4(0.f, 0.f, 0.f, 0.f);
        size_t off = 0;
        for (int L = 1; L <= Lcap; ++L) {
            const float4 v = ip[(size_t)(L - 1) * D4];
            acc.x += v.x; acc.y += v.y; acc.z += v.z; acc.w += v.w;
            op[off] = acc;
            off += (size_t)(S - L) * D4;
        }
    }
}

extern "C" void kernel_launch(void* const* d_in, const int* in_sizes, int n_in,
                              void* d_out, int out_size, void* d_ws, size_t ws_size,
                              hipStream_t stream) {
    const float* tensor = (const float*)d_in[0];
    const int* maxspan = (const int*)d_in[1];
    float* out = (float*)d_out;

    constexpr int B = 8, S = 512, D4 = 192;
    const int total = B * (S - 1) * D4;            // 784,896
    const int block = 256;
    const int grid = (total + block - 1) / block;  // 3066

    span_sums_kernel<<<grid, block, 0, stream>>>(
        (const float4*)tensor, (float4*)out, maxspan);
}